// Round 2
// baseline (652.642 us; speedup 1.0000x reference)
//
#include <hip/hip_runtime.h>

typedef _Float16 half8   __attribute__((ext_vector_type(8)));
typedef _Float16 half4_t __attribute__((ext_vector_type(4)));
typedef float    float4_t __attribute__((ext_vector_type(4)));

#define B_   8
#define N_   4096
#define C_   256
#define F_   64
#define NROW (B_ * N_)                 // 32768 rows total
#define OPHALF ((size_t)NROW * C_)     // elements per O-half (8.4M f16 = 16 MiB)

#if defined(__has_builtin) && __has_builtin(__builtin_amdgcn_exp2f)
#define EXP2(x) __builtin_amdgcn_exp2f(x)
#else
#define EXP2(x) exp2f(x)
#endif
#define LOG2E 1.44269504f

static __device__ __forceinline__ float4_t mfma16(half8 a, half8 b, float4_t c) {
  return __builtin_amdgcn_mfma_f32_16x16x32_f16(a, b, c, 0, 0, 0);
}

// DPP cross-lane within 16-lane rows: row_ror:N = 0x120|N.
template <int CTRL>
static __device__ __forceinline__ float dpp_f(float x) {
  return __int_as_float(__builtin_amdgcn_update_dpp(
      __float_as_int(x), __float_as_int(x), CTRL, 0xF, 0xF, false));
}
static __device__ __forceinline__ float row_max16(float v) {
  v = fmaxf(v, dpp_f<0x128>(v));
  v = fmaxf(v, dpp_f<0x124>(v));
  v = fmaxf(v, dpp_f<0x122>(v));
  v = fmaxf(v, dpp_f<0x121>(v));
  return v;
}
static __device__ __forceinline__ float row_sum16(float v) {
  v += dpp_f<0x128>(v);
  v += dpp_f<0x124>(v);
  v += dpp_f<0x122>(v);
  v += dpp_f<0x121>(v);
  return v;
}

// ---------------- prep: WhvT[d][c] = sum_e Wh[c][e]*Wv[e][d], f16 ----------------
__global__ __launch_bounds__(256) void prep_whvt(const float* __restrict__ Wh,
                                                 const float* __restrict__ Wv,
                                                 _Float16* __restrict__ whvt) {
  int d = blockIdx.x;
  int c = threadIdx.x;
  const float4_t* whr = (const float4_t*)(Wh + (size_t)c * 256);
  float acc = 0.f;
#pragma unroll 8
  for (int e4 = 0; e4 < 64; ++e4) {
    float4_t w4 = whr[e4];
    acc += w4[0] * Wv[(e4 * 4 + 0) * 256 + d];
    acc += w4[1] * Wv[(e4 * 4 + 1) * 256 + d];
    acc += w4[2] * Wv[(e4 * 4 + 2) * 256 + d];
    acc += w4[3] * Wv[(e4 * 4 + 3) * 256 + d];
  }
  whvt[d * 256 + c] = (_Float16)acc;
}

// ---- prep: wfgt[n][c] = (n<64 ? Wf[c][n]*log2e : Wg[c][n-64]), f16 --------------
// LOG2E folded into Wf so flash's S comes out of QK^T already in log2 domain.
__global__ __launch_bounds__(256) void prep_wfgt(const float* __restrict__ Wf,
                                                 const float* __restrict__ Wg,
                                                 _Float16* __restrict__ wfgt) {
  int n = blockIdx.x;
  int c = threadIdx.x;
  float v = (n < 64) ? Wf[c * 64 + n] * LOG2E : Wg[c * 64 + (n - 64)];
  wfgt[n * 256 + c] = (_Float16)v;
}

// ---------------- prep: xT[b][c][n] = (f16)x[b][n][c] ----------------------------
__global__ __launch_bounds__(256) void transpose_x(const float* __restrict__ x,
                                                   _Float16* __restrict__ xT) {
  __shared__ float tile[32][33];
  int b  = blockIdx.x >> 7;
  int n0 = (blockIdx.x & 127) << 5;
  int c0 = blockIdx.y << 5;
  int tid = threadIdx.x;
  int r  = tid >> 3;
  int cc = (tid & 7) << 2;
  const float* src = x + ((size_t)(b * N_ + n0 + r)) * C_ + c0 + cc;
  float4_t v = *(const float4_t*)src;
  tile[r][cc + 0] = v[0]; tile[r][cc + 1] = v[1];
  tile[r][cc + 2] = v[2]; tile[r][cc + 3] = v[3];
  __syncthreads();
  half4_t o;
  o[0] = (_Float16)tile[cc + 0][r];
  o[1] = (_Float16)tile[cc + 1][r];
  o[2] = (_Float16)tile[cc + 2][r];
  o[3] = (_Float16)tile[cc + 3][r];
  _Float16* dst = xT + ((size_t)(b * C_ + c0 + r)) * N_ + n0 + cc;
  *(half4_t*)dst = o;
}

// ---------------- f,g GEMM: [32768x256] @ wfgt^T -> f16 [32768x64] x2 ------------
__global__ __launch_bounds__(256) void fg_kernel(const float* __restrict__ x,
                                                 const _Float16* __restrict__ wfgt,
                                                 _Float16* __restrict__ f,
                                                 _Float16* __restrict__ g) {
  int tid  = threadIdx.x;
  int wave = tid >> 6, lane = tid & 63;
  int n16  = lane & 15, quad = lane >> 4;
  int row  = blockIdx.x * 64 + wave * 16 + n16;
  float4_t acc[8];
#pragma unroll
  for (int t = 0; t < 8; t++) acc[t] = (float4_t){0.f, 0.f, 0.f, 0.f};
  for (int k0 = 0; k0 < 256; k0 += 32) {
    const float* xp = x + (size_t)row * C_ + k0 + quad * 8;
    float4_t x0 = *(const float4_t*)xp;
    float4_t x1 = *(const float4_t*)(xp + 4);
    half8 af;
#pragma unroll
    for (int j = 0; j < 4; j++) { af[j] = (_Float16)x0[j]; af[4 + j] = (_Float16)x1[j]; }
#pragma unroll
    for (int t = 0; t < 8; t++) {
      half8 bf = *(const half8*)(wfgt + (size_t)(t * 16 + n16) * 256 + k0 + quad * 8);
      acc[t] = mfma16(af, bf, acc[t]);
    }
  }
  int orow = blockIdx.x * 64 + wave * 16 + quad * 4;
#pragma unroll
  for (int t = 0; t < 8; t++) {
#pragma unroll
    for (int r = 0; r < 4; r++) {
      _Float16 v = (_Float16)acc[t][r];
      int col = t * 16 + n16;
      if (t < 4) f[(size_t)(orow + r) * 64 + col] = v;
      else       g[(size_t)(orow + r) * 64 + col - 64] = v;
    }
  }
}

// ---------------- flash attention, 2-way KV split ---------------------------------
// grid (B, N/64, 2): blockIdx.z picks a 2048-wide j-half. Each block emits an
// UNNORMALIZED O-half (f16) plus per-row (m,l); out_kernel merges the halves.
// 1024 blocks -> 4 blocks/CU (vs 2), doubling waves/SIMD for latency hiding.
// Per-wave rescale-skip: if a wave's 16-row max didn't move this tile, all its
// alphas are exactly 1 and the 16x4 o_acc rescale for that row-tile is skipped.
__global__ __launch_bounds__(256, 4) void flash_kernel(const _Float16* __restrict__ f,
                                                       const _Float16* __restrict__ g,
                                                       const _Float16* __restrict__ xT,
                                                       _Float16* __restrict__ op,
                                                       float* __restrict__ ml) {
  __shared__ _Float16 ktb2[2][64 * 64];   // K tile, swizzled
  __shared__ _Float16 ptb2[2][64 * 64];   // P tile, swizzled
  __shared__ float alpha_lds[2][64];
  __shared__ int   aflag[2][4];           // per-wave "max moved" flags

  const int b   = blockIdx.x;
  const int i0  = blockIdx.y * 64;
  const int jh  = blockIdx.z;
  const int jbase = jh << 11;             // 0 or 2048
  const int tid = threadIdx.x;
  const int wave = tid >> 6, lane = tid & 63;
  const int n16 = lane & 15, quad = lane >> 4;
  const int nlo = n16 & 7, nhi = n16 >> 3;

  // Q fragments (A-layout: m=n16, k=quad*8+j); Q pre-scaled by log2e via prep
  half8 qf[2];
  {
    const _Float16* qp = f + (size_t)(b * N_ + i0 + wave * 16 + n16) * 64 + quad * 8;
    qf[0] = *(const half8*)qp;
    qf[1] = *(const half8*)(qp + 32);
  }

  float4_t o_acc[16];   // [ti*4+ct]: rows ti*16+4q+r, cols 64w+16ct+n16
#pragma unroll
  for (int t = 0; t < 16; t++) o_acc[t] = (float4_t){0.f, 0.f, 0.f, 0.f};
  float m_i[4] = {-1e30f, -1e30f, -1e30f, -1e30f};   // log2-domain running max
  float l_i[4] = {0.f, 0.f, 0.f, 0.f};

  const _Float16* gbase = g + (size_t)(b * N_) * 64;
  const _Float16* xbase = xT + ((size_t)b * C_ + 64 * wave) * (size_t)N_;

  const int krow = tid >> 2;
  const int kcb  = (tid & 3) << 1;
  const int krb  = krow & 7;

  // stage K tile for the first j-tile of this half
  {
    const _Float16* ks = gbase + (size_t)(jbase + krow) * 64 + (kcb << 3);
    half8 k0 = *(const half8*)ks;
    half8 k1 = *(const half8*)(ks + 8);
    _Float16* kd = ktb2[0] + krow * 64;
    *(half8*)(kd + (((kcb    ) ^ krb) << 3)) = k0;
    *(half8*)(kd + (((kcb + 1) ^ krb) << 3)) = k1;
  }
  __syncthreads();

  for (int k = 0; k < 32; ++k) {
    const int j0  = jbase + (k << 6);
    const int buf = k & 1;
    const int j0n = jbase + (((k + 1) & 31) << 6);

    // prefetch next K tile into regs
    half8 kp0, kp1;
    {
      const _Float16* ks = gbase + (size_t)(j0n + krow) * 64 + (kcb << 3);
      kp0 = *(const half8*)ks;
      kp1 = *(const half8*)(ks + 8);
    }
    // V fragments straight from global (L2)
    half8 vfr[8];
#pragma unroll
    for (int s = 0; s < 2; s++)
#pragma unroll
      for (int ct = 0; ct < 4; ct++)
        vfr[s * 4 + ct] = *(const half8*)(xbase + (size_t)(16 * ct + n16) * N_ +
                                          j0 + 32 * s + 8 * quad);

    // S = Q K^T (already log2-scaled)
    float4_t s_acc[4];
#pragma unroll
    for (int t = 0; t < 4; t++) s_acc[t] = (float4_t){0.f, 0.f, 0.f, 0.f};
    {
      const _Float16* ktb = ktb2[buf];
      __builtin_amdgcn_s_setprio(1);
#pragma unroll
      for (int s = 0; s < 2; s++)
#pragma unroll
        for (int t = 0; t < 4; t++) {
          half8 bf = *(const half8*)(ktb + (16 * t + n16) * 64 +
                                     (((4 * s + quad) ^ nlo) << 3));
          s_acc[t] = mfma16(qf[s], bf, s_acc[t]);
        }
      __builtin_amdgcn_s_setprio(0);
    }

    // online softmax (base-2); write P (swizzled) + alpha + flag to LDS
    float alpha_r[4];
#pragma unroll
    for (int r = 0; r < 4; r++) {
      float v = fmaxf(fmaxf(s_acc[0][r], s_acc[1][r]),
                      fmaxf(s_acc[2][r], s_acc[3][r]));
      v = row_max16(v);
      float mn = fmaxf(m_i[r], v);
      alpha_r[r] = EXP2(m_i[r] - mn);
      m_i[r] = mn;
    }
    {
      float am = fminf(fminf(alpha_r[0], alpha_r[1]),
                       fminf(alpha_r[2], alpha_r[3]));
      unsigned long long bm = __ballot(am < 1.0f);
      if (lane == 0) aflag[buf][wave] = (bm != 0ULL) ? 1 : 0;
    }
    _Float16* pb = ptb2[buf];
#pragma unroll
    for (int r = 0; r < 4; r++) {
      float s0 = EXP2(s_acc[0][r] - m_i[r]);
      float s1 = EXP2(s_acc[1][r] - m_i[r]);
      float s2 = EXP2(s_acc[2][r] - m_i[r]);
      float s3 = EXP2(s_acc[3][r] - m_i[r]);
      float v = row_sum16(s0 + s1 + s2 + s3);
      l_i[r] = l_i[r] * alpha_r[r] + v;
      const int row = wave * 16 + 4 * quad + r;
      const int rb  = row & 7;
      _Float16* pr = pb + row * 64 + nlo;
      pr[((nhi    ) ^ rb) << 3] = (_Float16)s0;
      pr[((nhi + 2) ^ rb) << 3] = (_Float16)s1;
      pr[((nhi + 4) ^ rb) << 3] = (_Float16)s2;
      pr[((nhi + 6) ^ rb) << 3] = (_Float16)s3;
    }
    if (n16 == 0) {
#pragma unroll
      for (int r = 0; r < 4; r++)
        alpha_lds[buf][wave * 16 + 4 * quad + r] = alpha_r[r];
    }
    // write prefetched K tile into other buffer
    {
      _Float16* kd = ktb2[buf ^ 1] + krow * 64;
      *(half8*)(kd + (((kcb    ) ^ krb) << 3)) = kp0;
      *(half8*)(kd + (((kcb + 1) ^ krb) << 3)) = kp1;
    }
    __syncthreads();

    // rescale O, skipping row-tiles whose max didn't move (alpha==1 exactly)
#pragma unroll
    for (int ti = 0; ti < 4; ti++) {
      if (aflag[buf][ti]) {
#pragma unroll
        for (int r = 0; r < 4; r++) {
          float al = alpha_lds[buf][ti * 16 + 4 * quad + r];
#pragma unroll
          for (int ct = 0; ct < 4; ct++) o_acc[ti * 4 + ct][r] *= al;
        }
      }
    }

    // O += P V
    __builtin_amdgcn_s_setprio(1);
#pragma unroll
    for (int s = 0; s < 2; s++)
#pragma unroll
      for (int ti = 0; ti < 4; ti++) {
        half8 af = *(const half8*)(pb + (16 * ti + n16) * 64 +
                                   (((4 * s + quad) ^ nlo) << 3));
#pragma unroll
        for (int ct = 0; ct < 4; ct++)
          o_acc[ti * 4 + ct] = mfma16(af, vfr[s * 4 + ct], o_acc[ti * 4 + ct]);
      }
    __builtin_amdgcn_s_setprio(0);
  }

  // emit unnormalized O-half + per-row (m,l); merge happens in out_kernel
  _Float16* ob = op + (size_t)jh * OPHALF;
#pragma unroll
  for (int ti = 0; ti < 4; ti++)
#pragma unroll
    for (int r = 0; r < 4; r++) {
      size_t orow = (size_t)(b * N_ + i0 + ti * 16 + 4 * quad + r) * C_;
#pragma unroll
      for (int ct = 0; ct < 4; ct++)
        ob[orow + 64 * wave + 16 * ct + n16] = (_Float16)o_acc[ti * 4 + ct][r];
    }
  if (n16 == 0) {
#pragma unroll
    for (int r = 0; r < 4; r++) {
      int rowg = b * N_ + i0 + wave * 16 + 4 * quad + r;
      ml[(size_t)(jh * 2 + 0) * NROW + rowg] = m_i[r];
      ml[(size_t)(jh * 2 + 1) * NROW + rowg] = l_i[r];
    }
  }
}

// ------- epilogue GEMM + softmax merge: out = gamma * (merge(O1,O2) @ Whv) + x ---
__global__ __launch_bounds__(256) void out_kernel(const _Float16* __restrict__ op,
                                                  const float* __restrict__ ml,
                                                  const _Float16* __restrict__ whvt,
                                                  const float* __restrict__ x,
                                                  const float* __restrict__ gamma,
                                                  float* __restrict__ out) {
  int tid  = threadIdx.x;
  int wave = tid >> 6, lane = tid & 63;
  int n16  = lane & 15, quad = lane >> 4;
  int row  = blockIdx.x * 64 + wave * 16 + n16;
  // per-row merge weights (computed once; f32 for accuracy)
  float m1 = ml[row],            l1 = ml[NROW + row];
  float m2 = ml[2 * NROW + row], l2 = ml[3 * NROW + row];
  float ms = fmaxf(m1, m2);
  float u1 = EXP2(m1 - ms), u2 = EXP2(m2 - ms);
  float inv = 1.f / (l1 * u1 + l2 * u2);
  float c1 = u1 * inv, c2 = u2 * inv;
  const _Float16* o1 = op + (size_t)row * C_;
  const _Float16* o2 = o1 + OPHALF;
  float4_t acc[16];
#pragma unroll
  for (int t = 0; t < 16; t++) acc[t] = (float4_t){0.f, 0.f, 0.f, 0.f};
  for (int k0 = 0; k0 < 256; k0 += 32) {
    half8 a1 = *(const half8*)(o1 + k0 + quad * 8);
    half8 a2 = *(const half8*)(o2 + k0 + quad * 8);
    half8 af;
#pragma unroll
    for (int j = 0; j < 8; j++)
      af[j] = (_Float16)((float)a1[j] * c1 + (float)a2[j] * c2);
#pragma unroll
    for (int t = 0; t < 16; t++) {
      half8 bf = *(const half8*)(whvt + (size_t)(t * 16 + n16) * 256 + k0 + quad * 8);
      acc[t] = mfma16(af, bf, acc[t]);
    }
  }
  float gm = gamma[0];
  int orow = blockIdx.x * 64 + wave * 16 + quad * 4;
#pragma unroll
  for (int t = 0; t < 16; t++) {
#pragma unroll
    for (int r = 0; r < 4; r++) {
      size_t idx = (size_t)(orow + r) * C_ + t * 16 + n16;
      out[idx] = gm * acc[t][r] + x[idx];
    }
  }
}

extern "C" void kernel_launch(void* const* d_in, const int* in_sizes, int n_in,
                              void* d_out, int out_size, void* d_ws, size_t ws_size,
                              hipStream_t stream) {
  const float* x     = (const float*)d_in[0];
  const float* Wf    = (const float*)d_in[1];
  const float* Wg    = (const float*)d_in[2];
  const float* Wh    = (const float*)d_in[3];
  const float* Wv    = (const float*)d_in[4];
  const float* gamma = (const float*)d_in[5];
  float* out = (float*)d_out;

  char* w = (char*)d_ws;
  _Float16* whvt = (_Float16*)(w);                                  // 128 KiB
  _Float16* wfgt = (_Float16*)(w + 131072);                         //  64 KiB
  _Float16* fb   = (_Float16*)(w + 196608);                         //   4 MiB
  _Float16* gb   = (_Float16*)(w + 196608 + 4194304);               //   4 MiB
  _Float16* xT   = (_Float16*)(w + 196608 + 2 * 4194304);           //  16 MiB
  _Float16* op   = (_Float16*)(w + 196608 + 2 * 4194304 + 16777216);//  32 MiB (2 halves)
  float*    ml   = (float*)   (w + 196608 + 2 * 4194304 + 16777216 + 33554432); // 512 KiB

  hipLaunchKernelGGL(prep_whvt,  dim3(256),     dim3(256), 0, stream, Wh, Wv, whvt);
  hipLaunchKernelGGL(prep_wfgt,  dim3(128),     dim3(256), 0, stream, Wf, Wg, wfgt);
  hipLaunchKernelGGL(transpose_x,dim3(1024, 8), dim3(256), 0, stream, x, xT);
  hipLaunchKernelGGL(fg_kernel,  dim3(512),     dim3(256), 0, stream, x, wfgt, fb, gb);
  hipLaunchKernelGGL(flash_kernel, dim3(8, 64, 2), dim3(256), 0, stream, fb, gb, xT, op, ml);
  hipLaunchKernelGGL(out_kernel, dim3(512),     dim3(256), 0, stream, op, ml, whvt, x, gamma, out);
}

// Round 3
// 313.448 us; speedup vs baseline: 2.0821x; 2.0821x over previous
//
#include <hip/hip_runtime.h>

typedef _Float16 half8   __attribute__((ext_vector_type(8)));
typedef _Float16 half4_t __attribute__((ext_vector_type(4)));
typedef float    float4_t __attribute__((ext_vector_type(4)));

#define B_   8
#define N_   4096
#define C_   256
#define F_   64
#define NROW (B_ * N_)                 // 32768 rows total
#define OPHALF ((size_t)NROW * C_)     // elements per O-half (8.4M f16 = 16 MiB)

#if defined(__has_builtin) && __has_builtin(__builtin_amdgcn_exp2f)
#define EXP2(x) __builtin_amdgcn_exp2f(x)
#else
#define EXP2(x) exp2f(x)
#endif
#define LOG2E 1.44269504f

static __device__ __forceinline__ float4_t mfma16(half8 a, half8 b, float4_t c) {
  return __builtin_amdgcn_mfma_f32_16x16x32_f16(a, b, c, 0, 0, 0);
}

// DPP cross-lane within 16-lane rows: row_ror:N = 0x120|N.
template <int CTRL>
static __device__ __forceinline__ float dpp_f(float x) {
  return __int_as_float(__builtin_amdgcn_update_dpp(
      __float_as_int(x), __float_as_int(x), CTRL, 0xF, 0xF, false));
}
static __device__ __forceinline__ float row_max16(float v) {
  v = fmaxf(v, dpp_f<0x128>(v));
  v = fmaxf(v, dpp_f<0x124>(v));
  v = fmaxf(v, dpp_f<0x122>(v));
  v = fmaxf(v, dpp_f<0x121>(v));
  return v;
}
static __device__ __forceinline__ float row_sum16(float v) {
  v += dpp_f<0x128>(v);
  v += dpp_f<0x124>(v);
  v += dpp_f<0x122>(v);
  v += dpp_f<0x121>(v);
  return v;
}

// ---------------- prep: WhvT[d][c] = sum_e Wh[c][e]*Wv[e][d], f16 ----------------
__global__ __launch_bounds__(256) void prep_whvt(const float* __restrict__ Wh,
                                                 const float* __restrict__ Wv,
                                                 _Float16* __restrict__ whvt) {
  int d = blockIdx.x;
  int c = threadIdx.x;
  const float4_t* whr = (const float4_t*)(Wh + (size_t)c * 256);
  float acc = 0.f;
#pragma unroll 8
  for (int e4 = 0; e4 < 64; ++e4) {
    float4_t w4 = whr[e4];
    acc += w4[0] * Wv[(e4 * 4 + 0) * 256 + d];
    acc += w4[1] * Wv[(e4 * 4 + 1) * 256 + d];
    acc += w4[2] * Wv[(e4 * 4 + 2) * 256 + d];
    acc += w4[3] * Wv[(e4 * 4 + 3) * 256 + d];
  }
  whvt[d * 256 + c] = (_Float16)acc;
}

// ---- prep: wfgt[n][c] = (n<64 ? Wf[c][n]*log2e : Wg[c][n-64]), f16 --------------
__global__ __launch_bounds__(256) void prep_wfgt(const float* __restrict__ Wf,
                                                 const float* __restrict__ Wg,
                                                 _Float16* __restrict__ wfgt) {
  int n = blockIdx.x;
  int c = threadIdx.x;
  float v = (n < 64) ? Wf[c * 64 + n] * LOG2E : Wg[c * 64 + (n - 64)];
  wfgt[n * 256 + c] = (_Float16)v;
}

// ---------------- prep: xT[b][c][n] = (f16)x[b][n][c] ----------------------------
__global__ __launch_bounds__(256) void transpose_x(const float* __restrict__ x,
                                                   _Float16* __restrict__ xT) {
  __shared__ float tile[32][33];
  int b  = blockIdx.x >> 7;
  int n0 = (blockIdx.x & 127) << 5;
  int c0 = blockIdx.y << 5;
  int tid = threadIdx.x;
  int r  = tid >> 3;
  int cc = (tid & 7) << 2;
  const float* src = x + ((size_t)(b * N_ + n0 + r)) * C_ + c0 + cc;
  float4_t v = *(const float4_t*)src;
  tile[r][cc + 0] = v[0]; tile[r][cc + 1] = v[1];
  tile[r][cc + 2] = v[2]; tile[r][cc + 3] = v[3];
  __syncthreads();
  half4_t o;
  o[0] = (_Float16)tile[cc + 0][r];
  o[1] = (_Float16)tile[cc + 1][r];
  o[2] = (_Float16)tile[cc + 2][r];
  o[3] = (_Float16)tile[cc + 3][r];
  _Float16* dst = xT + ((size_t)(b * C_ + c0 + r)) * N_ + n0 + cc;
  *(half4_t*)dst = o;
}

// ---------------- f,g GEMM: [32768x256] @ wfgt^T -> f16 [32768x64] x2 ------------
__global__ __launch_bounds__(256) void fg_kernel(const float* __restrict__ x,
                                                 const _Float16* __restrict__ wfgt,
                                                 _Float16* __restrict__ f,
                                                 _Float16* __restrict__ g) {
  int tid  = threadIdx.x;
  int wave = tid >> 6, lane = tid & 63;
  int n16  = lane & 15, quad = lane >> 4;
  int row  = blockIdx.x * 64 + wave * 16 + n16;
  float4_t acc[8];
#pragma unroll
  for (int t = 0; t < 8; t++) acc[t] = (float4_t){0.f, 0.f, 0.f, 0.f};
  for (int k0 = 0; k0 < 256; k0 += 32) {
    const float* xp = x + (size_t)row * C_ + k0 + quad * 8;
    float4_t x0 = *(const float4_t*)xp;
    float4_t x1 = *(const float4_t*)(xp + 4);
    half8 af;
#pragma unroll
    for (int j = 0; j < 4; j++) { af[j] = (_Float16)x0[j]; af[4 + j] = (_Float16)x1[j]; }
#pragma unroll
    for (int t = 0; t < 8; t++) {
      half8 bf = *(const half8*)(wfgt + (size_t)(t * 16 + n16) * 256 + k0 + quad * 8);
      acc[t] = mfma16(af, bf, acc[t]);
    }
  }
  int orow = blockIdx.x * 64 + wave * 16 + quad * 4;
#pragma unroll
  for (int t = 0; t < 8; t++) {
#pragma unroll
    for (int r = 0; r < 4; r++) {
      _Float16 v = (_Float16)acc[t][r];
      int col = t * 16 + n16;
      if (t < 4) f[(size_t)(orow + r) * 64 + col] = v;
      else       g[(size_t)(orow + r) * 64 + col - 64] = v;
    }
  }
}

// ---------------- flash attention, 2-way KV split ---------------------------------
// grid (B, N/64, 2): blockIdx.z picks a 2048-wide j-half. Each block emits an
// UNNORMALIZED O-half (f16) plus per-row (m,l); out_kernel merges the halves.
// __launch_bounds__(256, 2): natural ~160 unified VGPRs -> 3 blocks/CU, NO spill.
// ((256,4) forced 128 and spilled o_acc to scratch: 1.6 GB/dispatch HBM, 3.3x slower.)
__global__ __launch_bounds__(256, 2) void flash_kernel(const _Float16* __restrict__ f,
                                                       const _Float16* __restrict__ g,
                                                       const _Float16* __restrict__ xT,
                                                       _Float16* __restrict__ op,
                                                       float* __restrict__ ml) {
  __shared__ _Float16 ktb2[2][64 * 64];   // K tile, swizzled
  __shared__ _Float16 ptb2[2][64 * 64];   // P tile, swizzled
  __shared__ float alpha_lds[2][64];
  __shared__ int   aflag[2][4];           // per-wave "max moved" flags

  const int b   = blockIdx.x;
  const int i0  = blockIdx.y * 64;
  const int jh  = blockIdx.z;
  const int jbase = jh << 11;             // 0 or 2048
  const int tid = threadIdx.x;
  const int wave = tid >> 6, lane = tid & 63;
  const int n16 = lane & 15, quad = lane >> 4;
  const int nlo = n16 & 7, nhi = n16 >> 3;

  // Q fragments (A-layout: m=n16, k=quad*8+j); Q pre-scaled by log2e via prep
  half8 qf[2];
  {
    const _Float16* qp = f + (size_t)(b * N_ + i0 + wave * 16 + n16) * 64 + quad * 8;
    qf[0] = *(const half8*)qp;
    qf[1] = *(const half8*)(qp + 32);
  }

  float4_t o_acc[16];   // [ti*4+ct]: rows ti*16+4q+r, cols 64w+16ct+n16
#pragma unroll
  for (int t = 0; t < 16; t++) o_acc[t] = (float4_t){0.f, 0.f, 0.f, 0.f};
  float m_i[4] = {-1e30f, -1e30f, -1e30f, -1e30f};   // log2-domain running max
  float l_i[4] = {0.f, 0.f, 0.f, 0.f};

  const _Float16* gbase = g + (size_t)(b * N_) * 64;
  const _Float16* xbase = xT + ((size_t)b * C_ + 64 * wave) * (size_t)N_;

  const int krow = tid >> 2;
  const int kcb  = (tid & 3) << 1;
  const int krb  = krow & 7;

  // stage K tile for the first j-tile of this half
  {
    const _Float16* ks = gbase + (size_t)(jbase + krow) * 64 + (kcb << 3);
    half8 k0 = *(const half8*)ks;
    half8 k1 = *(const half8*)(ks + 8);
    _Float16* kd = ktb2[0] + krow * 64;
    *(half8*)(kd + (((kcb    ) ^ krb) << 3)) = k0;
    *(half8*)(kd + (((kcb + 1) ^ krb) << 3)) = k1;
  }
  __syncthreads();

  for (int k = 0; k < 32; ++k) {
    const int j0  = jbase + (k << 6);
    const int buf = k & 1;
    const int j0n = jbase + (((k + 1) & 31) << 6);

    // prefetch next K tile into regs
    half8 kp0, kp1;
    {
      const _Float16* ks = gbase + (size_t)(j0n + krow) * 64 + (kcb << 3);
      kp0 = *(const half8*)ks;
      kp1 = *(const half8*)(ks + 8);
    }
    // V fragments straight from global (L2/L3)
    half8 vfr[8];
#pragma unroll
    for (int s = 0; s < 2; s++)
#pragma unroll
      for (int ct = 0; ct < 4; ct++)
        vfr[s * 4 + ct] = *(const half8*)(xbase + (size_t)(16 * ct + n16) * N_ +
                                          j0 + 32 * s + 8 * quad);

    // S = Q K^T (already log2-scaled)
    float4_t s_acc[4];
#pragma unroll
    for (int t = 0; t < 4; t++) s_acc[t] = (float4_t){0.f, 0.f, 0.f, 0.f};
    {
      const _Float16* ktb = ktb2[buf];
      __builtin_amdgcn_s_setprio(1);
#pragma unroll
      for (int s = 0; s < 2; s++)
#pragma unroll
        for (int t = 0; t < 4; t++) {
          half8 bf = *(const half8*)(ktb + (16 * t + n16) * 64 +
                                     (((4 * s + quad) ^ nlo) << 3));
          s_acc[t] = mfma16(qf[s], bf, s_acc[t]);
        }
      __builtin_amdgcn_s_setprio(0);
    }

    // online softmax (base-2); write P (swizzled) + alpha + flag to LDS
    float alpha_r[4];
#pragma unroll
    for (int r = 0; r < 4; r++) {
      float v = fmaxf(fmaxf(s_acc[0][r], s_acc[1][r]),
                      fmaxf(s_acc[2][r], s_acc[3][r]));
      v = row_max16(v);
      float mn = fmaxf(m_i[r], v);
      alpha_r[r] = EXP2(m_i[r] - mn);
      m_i[r] = mn;
    }
    {
      float am = fminf(fminf(alpha_r[0], alpha_r[1]),
                       fminf(alpha_r[2], alpha_r[3]));
      unsigned long long bm = __ballot(am < 1.0f);
      if (lane == 0) aflag[buf][wave] = (bm != 0ULL) ? 1 : 0;
    }
    _Float16* pb = ptb2[buf];
#pragma unroll
    for (int r = 0; r < 4; r++) {
      float s0 = EXP2(s_acc[0][r] - m_i[r]);
      float s1 = EXP2(s_acc[1][r] - m_i[r]);
      float s2 = EXP2(s_acc[2][r] - m_i[r]);
      float s3 = EXP2(s_acc[3][r] - m_i[r]);
      float v = row_sum16(s0 + s1 + s2 + s3);
      l_i[r] = l_i[r] * alpha_r[r] + v;
      const int row = wave * 16 + 4 * quad + r;
      const int rb  = row & 7;
      _Float16* pr = pb + row * 64 + nlo;
      pr[((nhi    ) ^ rb) << 3] = (_Float16)s0;
      pr[((nhi + 2) ^ rb) << 3] = (_Float16)s1;
      pr[((nhi + 4) ^ rb) << 3] = (_Float16)s2;
      pr[((nhi + 6) ^ rb) << 3] = (_Float16)s3;
    }
    if (n16 == 0) {
#pragma unroll
      for (int r = 0; r < 4; r++)
        alpha_lds[buf][wave * 16 + 4 * quad + r] = alpha_r[r];
    }
    // write prefetched K tile into other buffer
    {
      _Float16* kd = ktb2[buf ^ 1] + krow * 64;
      *(half8*)(kd + (((kcb    ) ^ krb) << 3)) = kp0;
      *(half8*)(kd + (((kcb + 1) ^ krb) << 3)) = kp1;
    }
    __syncthreads();

    // rescale O, skipping row-tiles whose max didn't move (alpha==1 exactly)
#pragma unroll
    for (int ti = 0; ti < 4; ti++) {
      if (aflag[buf][ti]) {
#pragma unroll
        for (int r = 0; r < 4; r++) {
          float al = alpha_lds[buf][ti * 16 + 4 * quad + r];
#pragma unroll
          for (int ct = 0; ct < 4; ct++) o_acc[ti * 4 + ct][r] *= al;
        }
      }
    }

    // O += P V
    __builtin_amdgcn_s_setprio(1);
#pragma unroll
    for (int s = 0; s < 2; s++)
#pragma unroll
      for (int ti = 0; ti < 4; ti++) {
        half8 af = *(const half8*)(pb + (16 * ti + n16) * 64 +
                                   (((4 * s + quad) ^ nlo) << 3));
#pragma unroll
        for (int ct = 0; ct < 4; ct++)
          o_acc[ti * 4 + ct] = mfma16(af, vfr[s * 4 + ct], o_acc[ti * 4 + ct]);
      }
    __builtin_amdgcn_s_setprio(0);
  }

  // emit unnormalized O-half + per-row (m,l); merge happens in out_kernel
  _Float16* ob = op + (size_t)jh * OPHALF;
#pragma unroll
  for (int ti = 0; ti < 4; ti++)
#pragma unroll
    for (int r = 0; r < 4; r++) {
      size_t orow = (size_t)(b * N_ + i0 + ti * 16 + 4 * quad + r) * C_;
#pragma unroll
      for (int ct = 0; ct < 4; ct++)
        ob[orow + 64 * wave + 16 * ct + n16] = (_Float16)o_acc[ti * 4 + ct][r];
    }
  if (n16 == 0) {
#pragma unroll
    for (int r = 0; r < 4; r++) {
      int rowg = b * N_ + i0 + wave * 16 + 4 * quad + r;
      ml[(size_t)(jh * 2 + 0) * NROW + rowg] = m_i[r];
      ml[(size_t)(jh * 2 + 1) * NROW + rowg] = l_i[r];
    }
  }
}

// ------- epilogue GEMM + softmax merge: out = gamma * (merge(O1,O2) @ Whv) + x ---
__global__ __launch_bounds__(256) void out_kernel(const _Float16* __restrict__ op,
                                                  const float* __restrict__ ml,
                                                  const _Float16* __restrict__ whvt,
                                                  const float* __restrict__ x,
                                                  const float* __restrict__ gamma,
                                                  float* __restrict__ out) {
  int tid  = threadIdx.x;
  int wave = tid >> 6, lane = tid & 63;
  int n16  = lane & 15, quad = lane >> 4;
  int row  = blockIdx.x * 64 + wave * 16 + n16;
  // per-row merge weights (computed once; f32 for accuracy)
  float m1 = ml[row],            l1 = ml[NROW + row];
  float m2 = ml[2 * NROW + row], l2 = ml[3 * NROW + row];
  float ms = fmaxf(m1, m2);
  float u1 = EXP2(m1 - ms), u2 = EXP2(m2 - ms);
  float inv = 1.f / (l1 * u1 + l2 * u2);
  float c1 = u1 * inv, c2 = u2 * inv;
  const _Float16* o1 = op + (size_t)row * C_;
  const _Float16* o2 = o1 + OPHALF;
  float4_t acc[16];
#pragma unroll
  for (int t = 0; t < 16; t++) acc[t] = (float4_t){0.f, 0.f, 0.f, 0.f};
  for (int k0 = 0; k0 < 256; k0 += 32) {
    half8 a1 = *(const half8*)(o1 + k0 + quad * 8);
    half8 a2 = *(const half8*)(o2 + k0 + quad * 8);
    half8 af;
#pragma unroll
    for (int j = 0; j < 8; j++)
      af[j] = (_Float16)((float)a1[j] * c1 + (float)a2[j] * c2);
#pragma unroll
    for (int t = 0; t < 16; t++) {
      half8 bf = *(const half8*)(whvt + (size_t)(t * 16 + n16) * 256 + k0 + quad * 8);
      acc[t] = mfma16(af, bf, acc[t]);
    }
  }
  float gm = gamma[0];
  int orow = blockIdx.x * 64 + wave * 16 + quad * 4;
#pragma unroll
  for (int t = 0; t < 16; t++) {
#pragma unroll
    for (int r = 0; r < 4; r++) {
      size_t idx = (size_t)(orow + r) * C_ + t * 16 + n16;
      out[idx] = gm * acc[t][r] + x[idx];
    }
  }
}

extern "C" void kernel_launch(void* const* d_in, const int* in_sizes, int n_in,
                              void* d_out, int out_size, void* d_ws, size_t ws_size,
                              hipStream_t stream) {
  const float* x     = (const float*)d_in[0];
  const float* Wf    = (const float*)d_in[1];
  const float* Wg    = (const float*)d_in[2];
  const float* Wh    = (const float*)d_in[3];
  const float* Wv    = (const float*)d_in[4];
  const float* gamma = (const float*)d_in[5];
  float* out = (float*)d_out;

  char* w = (char*)d_ws;
  _Float16* whvt = (_Float16*)(w);                                  // 128 KiB
  _Float16* wfgt = (_Float16*)(w + 131072);                         //  64 KiB
  _Float16* fb   = (_Float16*)(w + 196608);                         //   4 MiB
  _Float16* gb   = (_Float16*)(w + 196608 + 4194304);               //   4 MiB
  _Float16* xT   = (_Float16*)(w + 196608 + 2 * 4194304);           //  16 MiB
  _Float16* op   = (_Float16*)(w + 196608 + 2 * 4194304 + 16777216);//  32 MiB (2 halves)
  float*    ml   = (float*)   (w + 196608 + 2 * 4194304 + 16777216 + 33554432); // 512 KiB

  hipLaunchKernelGGL(prep_whvt,  dim3(256),     dim3(256), 0, stream, Wh, Wv, whvt);
  hipLaunchKernelGGL(prep_wfgt,  dim3(128),     dim3(256), 0, stream, Wf, Wg, wfgt);
  hipLaunchKernelGGL(transpose_x,dim3(1024, 8), dim3(256), 0, stream, x, xT);
  hipLaunchKernelGGL(fg_kernel,  dim3(512),     dim3(256), 0, stream, x, wfgt, fb, gb);
  hipLaunchKernelGGL(flash_kernel, dim3(8, 64, 2), dim3(256), 0, stream, fb, gb, xT, op, ml);
  hipLaunchKernelGGL(out_kernel, dim3(512),     dim3(256), 0, stream, op, ml, whvt, x, gamma, out);
}